// Round 4
// baseline (197.035 us; speedup 1.0000x reference)
//
#include <hip/hip_runtime.h>
#include <hip/hip_bf16.h>
#include <math.h>

#define D_MODEL 32
#define S_LEN   2048
#define B_SZ    8
#define NTOK    (B_SZ * S_LEN)
#define LN_EPS  1e-5f
#define LOG2E   1.44269504088896340736f
#define QK_SCALE 0.35355339059327373f   /* 1/sqrt(8) */
#define MASKV   (-1.0e9f)               /* exp2(-1e9) == 0 */
#define CK      8                        /* keys per DMA chunk */

typedef const __attribute__((address_space(1))) void* gp_t;
typedef __attribute__((address_space(3))) void* sp_t;

__device__ __forceinline__ void dma16(const void* g, void* s) {
    __builtin_amdgcn_global_load_lds((gp_t)g, (sp_t)s, 16, 0, 0);
}
__device__ __forceinline__ void dma4(const void* g, void* s) {
    __builtin_amdgcn_global_load_lds((gp_t)g, (sp_t)s, 4, 0, 0);
}

// ---------------------------------------------------------------------------
__global__ void detect_mask_dtype(const unsigned char* __restrict__ mb,
                                  int* __restrict__ flag) {
    int t = threadIdx.x;  // 64 lanes
    unsigned char b1 = mb[t * 4 + 1];
    unsigned char b2 = mb[t * 4 + 2];
    unsigned char b3 = mb[t * 4 + 3];
    int ok = ((b1 | b2 | b3) == 0);
    unsigned long long vote = __ballot(ok);
    if (t == 0) flag[0] = (vote == ~0ULL) ? 1 : 0;   // 1 => int32 layout
}

// ---------------------------------------------------------------------------
// QKV projection: out = (x @ W + b) * scale.  Q gets 1/sqrt(8)*log2e folded in.
__global__ __launch_bounds__(256) void proj_kernel(
    const float* __restrict__ xQ, const float* __restrict__ xK,
    const float* __restrict__ xV,
    const float* __restrict__ WQ, const float* __restrict__ bQ,
    const float* __restrict__ WK, const float* __restrict__ bK,
    const float* __restrict__ WV, const float* __restrict__ bV,
    float* __restrict__ Qs, float* __restrict__ Ks, float* __restrict__ Vs)
{
    const float* x; const float* W; const float* bias; float* dst; float scale;
    if (blockIdx.y == 0)      { x = xQ; W = WQ; bias = bQ; dst = Qs; scale = QK_SCALE * LOG2E; }
    else if (blockIdx.y == 1) { x = xK; W = WK; bias = bK; dst = Ks; scale = 1.0f; }
    else                      { x = xV; W = WV; bias = bV; dst = Vs; scale = 1.0f; }

    __shared__ float xs[8][32];
    __shared__ float Ws[32][32];
    int t = threadIdx.x;
    long base = (long)blockIdx.x * 256;    // 8 rows x 32 cols
    xs[t >> 5][t & 31] = x[base + t];
#pragma unroll
    for (int i = 0; i < 4; ++i) {
        int f = i * 256 + t;
        Ws[f >> 5][f & 31] = W[f];
    }
    __syncthreads();
    int r = t >> 5, j = t & 31;
    float acc = bias[j];
#pragma unroll
    for (int i = 0; i < 32; ++i) acc = fmaf(xs[r][i], Ws[i][j], acc);
    dst[base + t] = acc * scale;
}

// ---------------------------------------------------------------------------
// Split-K flash attention, no-max variant (scores bounded, exp2 domain).
// 1 wave per block; lane -> (qg = lane>>2, h = lane&3); thread owns q-rows
// qg*4..qg*4+3 (wave covers 64 q-rows x 4 heads). K/V/mask staged via LDS DMA,
// double-buffered, counted vmcnt; mask DMA'd transposed [key][row] so one
// ds_read_b128 per key serves the thread's 4 rows.
template<int NSEG, bool I32>
__device__ __forceinline__ void attn_body(
    int lane, int b, int seg, int qt,
    const float* __restrict__ Qs, const float* __restrict__ Kb,
    const float* __restrict__ Vb, const void* __restrict__ mask,
    float* __restrict__ pl, float* __restrict__ pctx,
    float (*Kl)[CK * 32], float (*Vl)[CK * 32], int (*Ml)[CK * 64])
{
    constexpr int SEGLEN = S_LEN / NSEG;
    constexpr int NCH    = SEGLEN / CK;
    int qg = lane >> 2, h = lane & 3;
    int tok0 = qt * 64;                          // q-tile base within batch
    long tokbase = (long)b * S_LEN + tok0;
    int k0 = seg * SEGLEN;

    float4 qA[4], qB[4];
#pragma unroll
    for (int r = 0; r < 4; ++r) {
        const float* qp = Qs + (tokbase + qg * 4 + r) * 32 + h * 8;
        qA[r] = *(const float4*)qp;
        qB[r] = *(const float4*)(qp + 4);
    }

    const char* kg = (const char*)Kb + (size_t)k0 * 128 + lane * 16;
    const char* vg = (const char*)Vb + (size_t)k0 * 128 + lane * 16;
    const int*  mg = (const int*)mask + ((size_t)b * S_LEN + tok0 + lane) * S_LEN + k0;
    const unsigned char* m8 = (const unsigned char*)mask;

    // prologue: stage chunk 0 into buffer 0
    dma16(kg, &Kl[0][0]);
    dma16(vg, &Vl[0][0]);
    if (I32) {
#pragma unroll
        for (int j = 0; j < CK; ++j) dma4(mg + j, &Ml[0][j * 64]);
    }
    kg += CK * 128; vg += CK * 128; if (I32) mg += CK;

    float l[4] = {0.f, 0.f, 0.f, 0.f};
    float c[4][8];
#pragma unroll
    for (int r = 0; r < 4; ++r)
#pragma unroll
        for (int e = 0; e < 8; ++e) c[r][e] = 0.f;

#pragma unroll 1
    for (int ch = 0; ch < NCH; ++ch) {
        int cur = ch & 1, nxt = cur ^ 1;

        int2 mrow[4];
        if (!I32) {
#pragma unroll
            for (int r = 0; r < 4; ++r)
                mrow[r] = *(const int2*)(m8 + (size_t)(tokbase + qg * 4 + r) * S_LEN
                                            + k0 + ch * CK);
        }

        if (ch + 1 < NCH) {
            dma16(kg, &Kl[nxt][0]);
            dma16(vg, &Vl[nxt][0]);
            if (I32) {
#pragma unroll
                for (int j = 0; j < CK; ++j) dma4(mg + j, &Ml[nxt][j * 64]);
                kg += CK * 128; vg += CK * 128; mg += CK;
                asm volatile("s_waitcnt vmcnt(10)" ::: "memory");
            } else {
                kg += CK * 128; vg += CK * 128;
                asm volatile("s_waitcnt vmcnt(0)" ::: "memory");
            }
        } else {
            asm volatile("s_waitcnt vmcnt(0)" ::: "memory");
        }

#pragma unroll
        for (int k = 0; k < CK; ++k) {
            const float* Kc = &Kl[cur][k * 32 + h * 8];
            float4 ka = *(const float4*)Kc;
            float4 kb = *(const float4*)(Kc + 4);
            const float* Vc = &Vl[cur][k * 32 + h * 8];
            float4 va = *(const float4*)Vc;
            float4 vb = *(const float4*)(Vc + 4);

            int mk[4];
            if (I32) {
                int4 mq = *(const int4*)&Ml[cur][k * 64 + qg * 4];
                mk[0] = mq.x; mk[1] = mq.y; mk[2] = mq.z; mk[3] = mq.w;
            } else {
#pragma unroll
                for (int r = 0; r < 4; ++r) {
                    int w = (k < 4) ? mrow[r].x : mrow[r].y;
                    mk[r] = (w >> ((k & 3) * 8)) & 255;
                }
            }

            float p[4];
#pragma unroll
            for (int r = 0; r < 4; ++r) {
                float s = qA[r].x * ka.x;
                s = fmaf(qA[r].y, ka.y, s);
                s = fmaf(qA[r].z, ka.z, s);
                s = fmaf(qA[r].w, ka.w, s);
                s = fmaf(qB[r].x, kb.x, s);
                s = fmaf(qB[r].y, kb.y, s);
                s = fmaf(qB[r].z, kb.z, s);
                s = fmaf(qB[r].w, kb.w, s);
                s = mk[r] ? MASKV : s;
                p[r] = exp2f(s);
                l[r] += p[r];
            }
#pragma unroll
            for (int r = 0; r < 4; ++r) {
                c[r][0] = fmaf(p[r], va.x, c[r][0]);
                c[r][1] = fmaf(p[r], va.y, c[r][1]);
                c[r][2] = fmaf(p[r], va.z, c[r][2]);
                c[r][3] = fmaf(p[r], va.w, c[r][3]);
                c[r][4] = fmaf(p[r], vb.x, c[r][4]);
                c[r][5] = fmaf(p[r], vb.y, c[r][5]);
                c[r][6] = fmaf(p[r], vb.z, c[r][6]);
                c[r][7] = fmaf(p[r], vb.w, c[r][7]);
            }
        }
    }

#pragma unroll
    for (int r = 0; r < 4; ++r) {
        long tok = tokbase + qg * 4 + r;
        pl[(size_t)seg * NTOK * 4 + tok * 4 + h] = l[r];
        float* pc = pctx + ((size_t)seg * NTOK + tok) * 32 + h * 8;
        *(float4*)(pc)     = make_float4(c[r][0], c[r][1], c[r][2], c[r][3]);
        *(float4*)(pc + 4) = make_float4(c[r][4], c[r][5], c[r][6], c[r][7]);
    }
}

template<int NSEG>
__global__ __launch_bounds__(64, 4) void attn_kernel(
    const float* __restrict__ Qs, const float* __restrict__ Ks,
    const float* __restrict__ Vs, const void* __restrict__ mask,
    const int* __restrict__ flag_p,
    float* __restrict__ pl, float* __restrict__ pctx)
{
    __shared__ float Kl[2][CK * 32];
    __shared__ float Vl[2][CK * 32];
    __shared__ int   Ml[2][CK * 64];

    const int nb = NSEG * 32;                   // blocks per batch
    int raw = blockIdx.x;
    int cpx = (B_SZ * nb) / 8;
    int cid = (raw & 7) * cpx + (raw >> 3);     // XCD-contiguous
    int b   = cid / nb;
    int rem = cid - b * nb;
    int seg = rem >> 5;
    int qt  = rem & 31;
    int lane = threadIdx.x;

    const float* Kb = Ks + (long)b * S_LEN * 32;
    const float* Vb = Vs + (long)b * S_LEN * 32;

    if (flag_p[0])
        attn_body<NSEG, true >(lane, b, seg, qt, Qs, Kb, Vb, mask, pl, pctx, Kl, Vl, Ml);
    else
        attn_body<NSEG, false>(lane, b, seg, qt, Qs, Kb, Vb, mask, pl, pctx, Kl, Vl, Ml);
}

// ---------------------------------------------------------------------------
// Merge split-K partials (plain sums; no max needed) -> sa; then
// attn_output = sa@WO + bO + resid; LayerNorm.
template<int NSEG>
__global__ __launch_bounds__(256) void combine_epilogue(
    const float* __restrict__ pl, const float* __restrict__ pctx,
    const float* __restrict__ WO, const float* __restrict__ bO,
    const float* __restrict__ resid,
    float* __restrict__ sa_out, float* __restrict__ out0)
{
    __shared__ float sas[8][32];
    __shared__ float Ws[32][32];
    int t = threadIdx.x;
    long base = (long)blockIdx.x * 256;      // 8 tokens x 32
    int r = t >> 5, j = t & 31;
    long tok = (long)blockIdx.x * 8 + r;
    int h = j >> 3;

#pragma unroll
    for (int i = 0; i < 4; ++i) {
        int f = i * 256 + t;
        Ws[f >> 5][f & 31] = WO[f];
    }

    float L = 0.f, ctx = 0.f;
#pragma unroll
    for (int s2 = 0; s2 < NSEG; ++s2) {
        L   += pl[(size_t)s2 * NTOK * 4 + tok * 4 + h];
        ctx += pctx[((size_t)s2 * NTOK + tok) * 32 + j];
    }
    float sa = ctx / L;
    sa_out[base + t] = sa;
    sas[r][j] = sa;
    __syncthreads();

    float y = bO[j] + resid[base + t];
#pragma unroll
    for (int i = 0; i < 32; ++i) y = fmaf(sas[r][i], Ws[i][j], y);

    float sum = y;
#pragma unroll
    for (int o = 16; o >= 1; o >>= 1) sum += __shfl_xor(sum, o, 32);
    float mu = sum * (1.0f / 32.0f);
    float d  = y - mu;
    float sq = d * d;
#pragma unroll
    for (int o = 16; o >= 1; o >>= 1) sq += __shfl_xor(sq, o, 32);
    float var = sq * (1.0f / 32.0f);
    out0[base + t] = d * rsqrtf(var + LN_EPS);
}

// ---------------------------------------------------------------------------
extern "C" void kernel_launch(void* const* d_in, const int* in_sizes, int n_in,
                              void* d_out, int out_size, void* d_ws, size_t ws_size,
                              hipStream_t stream)
{
    const float* inQ = (const float*)d_in[0];
    const float* inK = (const float*)d_in[1];
    const float* inV = (const float*)d_in[2];
    const void*  mask = d_in[3];
    const float* WQ = (const float*)d_in[4];
    const float* bQ = (const float*)d_in[5];
    const float* WK = (const float*)d_in[6];
    const float* bK = (const float*)d_in[7];
    const float* WV = (const float*)d_in[8];
    const float* bV = (const float*)d_in[9];
    const float* WO = (const float*)d_in[10];
    const float* bO = (const float*)d_in[11];

    float* out0 = (float*)d_out;                    // layernorm output
    float* sa   = (float*)d_out + (long)NTOK * 32;  // self_attn output

    char* ws   = (char*)d_ws;
    int*  flag = (int*)ws;
    float* Qs  = (float*)(ws + 256);
    float* Ks  = Qs + (long)NTOK * 32;
    float* Vs  = Ks + (long)NTOK * 32;
    float* pbase = Vs + (long)NTOK * 32;

    // per-seg partials: pl (NTOK*4) + pctx (NTOK*32) floats
    size_t fixed  = 256 + 3ul * NTOK * 32 * 4;
    size_t perseg = (size_t)NTOK * 36 * 4;
    int NS = 1;
    if      (fixed + 16 * perseg <= ws_size) NS = 16;
    else if (fixed +  8 * perseg <= ws_size) NS = 8;
    else if (fixed +  4 * perseg <= ws_size) NS = 4;
    else if (fixed +  2 * perseg <= ws_size) NS = 2;

    float* pl   = pbase;
    float* pctx = pl + (long)NS * NTOK * 4;

    detect_mask_dtype<<<1, 64, 0, stream>>>((const unsigned char*)mask, flag);
    proj_kernel<<<dim3(NTOK / 8, 3), 256, 0, stream>>>(
        inQ, inK, inV, WQ, bQ, WK, bK, WV, bV, Qs, Ks, Vs);

    int agrid = B_SZ * NS * 32;
    int cgrid = NTOK / 8;
    switch (NS) {
    case 16:
        attn_kernel<16><<<agrid, 64, 0, stream>>>(Qs, Ks, Vs, mask, flag, pl, pctx);
        combine_epilogue<16><<<cgrid, 256, 0, stream>>>(pl, pctx, WO, bO, inQ, sa, out0);
        break;
    case 8:
        attn_kernel<8><<<agrid, 64, 0, stream>>>(Qs, Ks, Vs, mask, flag, pl, pctx);
        combine_epilogue<8><<<cgrid, 256, 0, stream>>>(pl, pctx, WO, bO, inQ, sa, out0);
        break;
    case 4:
        attn_kernel<4><<<agrid, 64, 0, stream>>>(Qs, Ks, Vs, mask, flag, pl, pctx);
        combine_epilogue<4><<<cgrid, 256, 0, stream>>>(pl, pctx, WO, bO, inQ, sa, out0);
        break;
    case 2:
        attn_kernel<2><<<agrid, 64, 0, stream>>>(Qs, Ks, Vs, mask, flag, pl, pctx);
        combine_epilogue<2><<<cgrid, 256, 0, stream>>>(pl, pctx, WO, bO, inQ, sa, out0);
        break;
    default:
        attn_kernel<1><<<agrid, 64, 0, stream>>>(Qs, Ks, Vs, mask, flag, pl, pctx);
        combine_epilogue<1><<<cgrid, 256, 0, stream>>>(pl, pctx, WO, bO, inQ, sa, out0);
        break;
    }
}